// Round 2
// baseline (5456.043 us; speedup 1.0000x reference)
//
#include <hip/hip_runtime.h>

typedef _Float16 h8 __attribute__((ext_vector_type(8)));
typedef _Float16 h4 __attribute__((ext_vector_type(4)));
typedef float    f4 __attribute__((ext_vector_type(4)));

#define NT     512
#define OUT0   33554432   // 64*512*1024

__device__ __forceinline__ float sigm(float x)  { return 1.0f / (1.0f + __expf(-x)); }
__device__ __forceinline__ float tanhf_(float x){ float e = __expf(2.0f * x); return 1.0f - 2.0f / (e + 1.0f); }

// ---------------- prep kernels ----------------

__global__ __launch_bounds__(256) void xconv_k(const float* __restrict__ x, _Float16* __restrict__ x16) {
    size_t i = ((size_t)blockIdx.x * 256 + threadIdx.x) * 4;
    f4 v = *(const f4*)(x + i);
    h4 o; o[0] = (_Float16)v[0]; o[1] = (_Float16)v[1]; o[2] = (_Float16)v[2]; o[3] = (_Float16)v[3];
    *(h4*)(x16 + i) = o;
}

// wcat16[dir][p][k], p = j*4 + gate, k<512 -> Wih, else Whh
__global__ __launch_bounds__(256) void wconv_k(const float* __restrict__ Wih_f, const float* __restrict__ Whh_f,
                                               const float* __restrict__ Wih_b, const float* __restrict__ Whh_b,
                                               _Float16* __restrict__ wcat) {
    size_t e = (size_t)blockIdx.x * 256 + threadIdx.x;
    int k4  = (int)(e & 255);
    int p   = (int)((e >> 8) & 2047);
    int dir = (int)(e >> 19);
    int gate = p & 3, j = p >> 2;
    int k = k4 * 4;
    const float* Wih = dir ? Wih_b : Wih_f;
    const float* Whh = dir ? Whh_b : Whh_f;
    f4 v;
    if (k < 512) v = *(const f4*)&Wih[((size_t)gate * 512 + j) * 512 + k];
    else         v = *(const f4*)&Whh[((size_t)gate * 512 + j) * 512 + (k - 512)];
    h4 o; o[0] = (_Float16)v[0]; o[1] = (_Float16)v[1]; o[2] = (_Float16)v[2]; o[3] = (_Float16)v[3];
    *(h4*)&wcat[(((size_t)dir * 2048) + p) * 1024 + k] = o;
}

// h0 -> h16 buf0 (fp16), zero barrier counters
__global__ __launch_bounds__(256) void init2_k(const float* __restrict__ enc_h,
                                               _Float16* __restrict__ h16, unsigned* __restrict__ cnt) {
    int e = blockIdx.x * 256 + threadIdx.x;   // 0..65535
    float v = enc_h[e];
    int b = e >> 10, q = e & 1023, dir = q >> 9, j = q & 511;
    h16[((size_t)(dir * 64 + b)) * 512 + j] = (_Float16)v;
    if (e < 4096) cnt[e] = 0;
}

// ---------------- persistent bidirectional LSTM scan ----------------
// 256 blocks (1/CU): bx = [dir(1)][mg(2)][ng(5)]. Block: M=16 batches (mg),
// N=64 gate rows (ng), K=1024. 4 waves split K (256 each: 128 x-part + 128 h-part).
// Weights: 128 VGPRs/wave, resident all 512 steps. c-state: 1 reg/thread.
// Sync: per-(dir,mg) 32-block barrier, one per step, ping-pong h16 buffers.
__global__ __launch_bounds__(256, 1) void lstm_persist(
    const _Float16* __restrict__ x16, const _Float16* __restrict__ wcat,
    const float* __restrict__ b_f, const float* __restrict__ b_b,
    const float* __restrict__ enc_c,
    _Float16* __restrict__ h16,          // [2 buf][2 dir][64][512]
    float* __restrict__ out, float* __restrict__ hseg, float* __restrict__ cseg,
    unsigned* __restrict__ cnt)          // [2 dir][4 mg][512 t]
{
    const int bx  = blockIdx.x;
    const int dir = bx >> 7, mg = (bx >> 5) & 3, ng = bx & 31;
    const int b0 = mg * 16, p0 = ng * 64, j0 = ng * 16;
    const int tid = threadIdx.x, lane = tid & 63, kw = tid >> 6;
    const int l15 = lane & 15, koff = (lane >> 4) * 8;

    __shared__ __align__(16) _Float16 z[16][1032];   // [batch][k: 0-511 x | 512-1023 h], stride 516 dw -> 2-way max
    __shared__ float gbuf[4][16][68];                // [wave][m][p_local] partial gates

    // ---- one-time: B fragments into registers (wave kw covers k in [kw*128, kw*128+128) of each half) ----
    h8 bfx[4][4], bfh[4][4];
    #pragma unroll
    for (int nt = 0; nt < 4; ++nt) {
        const _Float16* wrow = &wcat[((size_t)dir * 2048 + p0 + nt * 16 + l15) * 1024];
        #pragma unroll
        for (int s = 0; s < 4; ++s) {
            bfx[nt][s] = *(const h8*)&wrow[kw * 128 + s * 32 + koff];
            bfh[nt][s] = *(const h8*)&wrow[512 + kw * 128 + s * 32 + koff];
        }
    }

    // ---- one-time: per-thread epilogue state (thread owns (b0+mb, j0+jj)) ----
    const int mb = tid >> 4, jj = tid & 15;
    const float* bias = dir ? b_b : b_f;
    const float bi = bias[0 * 512 + j0 + jj];
    const float bf = bias[1 * 512 + j0 + jj];
    const float bg = bias[2 * 512 + j0 + jj];
    const float bo = bias[3 * 512 + j0 + jj];
    float c = enc_c[(size_t)(b0 + mb) * 1024 + dir * 512 + j0 + jj];
    float hlast = 0.f;

    unsigned* mycnt = cnt + ((size_t)dir * 4 + mg) * 512;

    // prefetch x_0
    h8 xr[4];
    {
        const int tx0 = dir ? (NT - 1) : 0;
        #pragma unroll
        for (int it = 0; it < 4; ++it) {
            int e = tid + 256 * it, r = e >> 6, c8 = e & 63;
            xr[it] = *(const h8*)&x16[((size_t)(b0 + r) * NT + tx0) * 512 + c8 * 8];
        }
    }

    for (int t = 0; t < NT; ++t) {
        const int tx = dir ? (NT - 1 - t) : t;

        // ---- stage x_t from prefetch regs ----
        #pragma unroll
        for (int it = 0; it < 4; ++it) {
            int e = tid + 256 * it, r = e >> 6, c8 = e & 63;
            *(h8*)&z[r][c8 * 8] = xr[it];
        }
        __syncthreads();

        // ---- x-part MFMAs (no dependence on h -> overlaps barrier propagation) ----
        f4 acc[4];
        #pragma unroll
        for (int nt = 0; nt < 4; ++nt) { acc[nt][0] = 0.f; acc[nt][1] = 0.f; acc[nt][2] = 0.f; acc[nt][3] = 0.f; }
        #pragma unroll
        for (int s = 0; s < 4; ++s) {
            h8 a = *(const h8*)&z[l15][kw * 128 + s * 32 + koff];
            #pragma unroll
            for (int nt = 0; nt < 4; ++nt)
                acc[nt] = __builtin_amdgcn_mfma_f32_16x16x32_f16(a, bfx[nt][s], acc[nt], 0, 0, 0);
        }

        // ---- wait for h(t-1) from the other 31 blocks of this (dir,mg) group ----
        if (tid == 0 && t > 0) {
            while (__hip_atomic_load(&mycnt[t - 1], __ATOMIC_RELAXED, __HIP_MEMORY_SCOPE_AGENT) < 32u)
                __builtin_amdgcn_s_sleep(1);
            (void)__hip_atomic_load(&mycnt[t - 1], __ATOMIC_ACQUIRE, __HIP_MEMORY_SCOPE_AGENT);
        }
        __syncthreads();

        // ---- stage h(t-1) ----
        const _Float16* hsrc = h16 + ((size_t)(t & 1) * 2 + dir) * 64 * 512;
        #pragma unroll
        for (int it = 0; it < 4; ++it) {
            int e = tid + 256 * it, r = e >> 6, c8 = e & 63;
            *(h8*)&z[r][512 + c8 * 8] = *(const h8*)&hsrc[(size_t)(b0 + r) * 512 + c8 * 8];
        }
        __syncthreads();

        // ---- h-part MFMAs ----
        #pragma unroll
        for (int s = 0; s < 4; ++s) {
            h8 a = *(const h8*)&z[l15][512 + kw * 128 + s * 32 + koff];
            #pragma unroll
            for (int nt = 0; nt < 4; ++nt)
                acc[nt] = __builtin_amdgcn_mfma_f32_16x16x32_f16(a, bfh[nt][s], acc[nt], 0, 0, 0);
        }

        // ---- prefetch x_{t+1}: latency hides behind epilogue + barrier ----
        if (t + 1 < NT) {
            const int tx2 = dir ? (NT - 2 - t) : (t + 1);
            #pragma unroll
            for (int it = 0; it < 4; ++it) {
                int e = tid + 256 * it, r = e >> 6, c8 = e & 63;
                xr[it] = *(const h8*)&x16[((size_t)(b0 + r) * NT + tx2) * 512 + c8 * 8];
            }
        }

        // ---- cross-wave split-K reduction via LDS ----
        #pragma unroll
        for (int nt = 0; nt < 4; ++nt)
            #pragma unroll
            for (int r = 0; r < 4; ++r)
                gbuf[kw][(lane >> 4) * 4 + r][nt * 16 + l15] = acc[nt][r];
        __syncthreads();

        // ---- gates + state update (thread = (mb, jj)) ----
        float gi = bi, gf = bf, gg = bg, go = bo;
        #pragma unroll
        for (int w = 0; w < 4; ++w) {
            gi += gbuf[w][mb][jj * 4 + 0];
            gf += gbuf[w][mb][jj * 4 + 1];
            gg += gbuf[w][mb][jj * 4 + 2];
            go += gbuf[w][mb][jj * 4 + 3];
        }
        float i_ = sigm(gi), f_ = sigm(gf), o_ = sigm(go), g_ = tanhf_(gg);
        c = f_ * c + i_ * g_;
        float h = o_ * tanhf_(c);
        hlast = h;

        _Float16* hdst = h16 + ((size_t)((t + 1) & 1) * 2 + dir) * 64 * 512;
        hdst[(size_t)(b0 + mb) * 512 + j0 + jj] = (_Float16)h;
        out[((size_t)(b0 + mb) * NT + tx) * 1024 + dir * 512 + j0 + jj] = h;

        __syncthreads();   // all threads' h16 stores drained (vmcnt(0) before s_barrier) + gbuf reuse guard
        if (tid == 0 && t + 1 < NT)
            __hip_atomic_fetch_add(&mycnt[t], 1u, __ATOMIC_RELEASE, __HIP_MEMORY_SCOPE_AGENT);
    }

    // ---- final h/c state ----
    hseg[(size_t)(b0 + mb) * 1024 + dir * 512 + j0 + jj] = hlast;
    cseg[(size_t)(b0 + mb) * 1024 + dir * 512 + j0 + jj] = c;
}

// ---------------- launcher ----------------

extern "C" void kernel_launch(void* const* d_in, const int* in_sizes, int n_in,
                              void* d_out, int out_size, void* d_ws, size_t ws_size,
                              hipStream_t stream) {
    const float* xin   = (const float*)d_in[0];
    const float* enc_h = (const float*)d_in[1];
    const float* enc_c = (const float*)d_in[2];
    const float* Wih_f = (const float*)d_in[3];
    const float* Whh_f = (const float*)d_in[4];
    const float* b_f   = (const float*)d_in[5];
    const float* Wih_b = (const float*)d_in[6];
    const float* Whh_b = (const float*)d_in[7];
    const float* b_b   = (const float*)d_in[8];

    float* out  = (float*)d_out;
    float* hseg = out + OUT0;          // final h [64,1024]
    float* cseg = hseg + 65536;        // final c [64,1024]

    const size_t X16_BYTES  = (size_t)64 * 512 * 512 * 2;        // 33,554,432
    const size_t WCAT_BYTES = (size_t)2 * 2048 * 1024 * 2;       //  8,388,608
    const size_t H16_BYTES  = (size_t)2 * 2 * 64 * 512 * 2;      //    262,144

    _Float16* x16  = (_Float16*)d_ws;
    _Float16* wcat = (_Float16*)((char*)d_ws + X16_BYTES);
    _Float16* h16  = (_Float16*)((char*)d_ws + X16_BYTES + WCAT_BYTES);
    unsigned* cnt  = (unsigned*)((char*)d_ws + X16_BYTES + WCAT_BYTES + H16_BYTES);

    xconv_k<<<dim3(16384), dim3(256), 0, stream>>>(xin, x16);
    wconv_k<<<dim3(4096), dim3(256), 0, stream>>>(Wih_f, Whh_f, Wih_b, Whh_b, wcat);
    init2_k<<<dim3(256), dim3(256), 0, stream>>>(enc_h, h16, cnt);
    lstm_persist<<<dim3(256), dim3(256), 0, stream>>>(x16, wcat, b_f, b_b, enc_c,
                                                      h16, out, hseg, cseg, cnt);
}

// Round 3
// 3973.297 us; speedup vs baseline: 1.3732x; 1.3732x over previous
//
#include <hip/hip_runtime.h>

typedef _Float16 h8 __attribute__((ext_vector_type(8)));
typedef _Float16 h4 __attribute__((ext_vector_type(4)));
typedef float    f4 __attribute__((ext_vector_type(4)));

#define NT     512
#define OUT0   33554432   // 64*512*1024

__device__ __forceinline__ float sigm(float x)  { return 1.0f / (1.0f + __expf(-x)); }
__device__ __forceinline__ float tanhf_(float x){ float e = __expf(2.0f * x); return 1.0f - 2.0f / (e + 1.0f); }

// ---------------- prep kernels ----------------

__global__ __launch_bounds__(256) void xconv_k(const float* __restrict__ x, _Float16* __restrict__ x16) {
    size_t i = ((size_t)blockIdx.x * 256 + threadIdx.x) * 4;
    f4 v = *(const f4*)(x + i);
    h4 o; o[0] = (_Float16)v[0]; o[1] = (_Float16)v[1]; o[2] = (_Float16)v[2]; o[3] = (_Float16)v[3];
    *(h4*)(x16 + i) = o;
}

// wcat16[dir][p][k], p = j*4 + gate, k<512 -> Wih, else Whh
__global__ __launch_bounds__(256) void wconv_k(const float* __restrict__ Wih_f, const float* __restrict__ Whh_f,
                                               const float* __restrict__ Wih_b, const float* __restrict__ Whh_b,
                                               _Float16* __restrict__ wcat) {
    size_t e = (size_t)blockIdx.x * 256 + threadIdx.x;
    int k4  = (int)(e & 255);
    int p   = (int)((e >> 8) & 2047);
    int dir = (int)(e >> 19);
    int gate = p & 3, j = p >> 2;
    int k = k4 * 4;
    const float* Wih = dir ? Wih_b : Wih_f;
    const float* Whh = dir ? Whh_b : Whh_f;
    f4 v;
    if (k < 512) v = *(const f4*)&Wih[((size_t)gate * 512 + j) * 512 + k];
    else         v = *(const f4*)&Whh[((size_t)gate * 512 + j) * 512 + (k - 512)];
    h4 o; o[0] = (_Float16)v[0]; o[1] = (_Float16)v[1]; o[2] = (_Float16)v[2]; o[3] = (_Float16)v[3];
    *(h4*)&wcat[(((size_t)dir * 2048) + p) * 1024 + k] = o;
}

// h0 -> h16 buf0 (fp16), zero flags
__global__ __launch_bounds__(256) void init2_k(const float* __restrict__ enc_h,
                                               _Float16* __restrict__ h16, unsigned* __restrict__ flg) {
    int e = blockIdx.x * 256 + threadIdx.x;   // 0..65535
    float v = enc_h[e];
    int b = e >> 10, q = e & 1023, dir = q >> 9, j = q & 511;
    h16[((size_t)(dir * 64 + b)) * 512 + j] = (_Float16)v;
    if (e < 4096) flg[e] = 0;
}

// ---------------- persistent bidirectional LSTM scan ----------------
// 256 blocks (1/CU): bx = [dir(1)][mg(2)][ng(5)]. Block: M=16 batches, N=64 gate
// rows, K=1024; 4 waves split K (256 each). Weights pinned in VGPRs all 512 steps.
// Sync: per-(dir,mg) group of 128 wave-flags (u16 = t+1), written/read only via
// sc0 sc1 (device-coherent, L2-bypass) asm ops -> no cache-wide flush/invalidate.
__global__ __launch_bounds__(256, 1) void lstm_persist(
    const _Float16* __restrict__ x16, const _Float16* __restrict__ wcat,
    const float* __restrict__ b_f, const float* __restrict__ b_b,
    const float* __restrict__ enc_c,
    _Float16* __restrict__ h16,          // [2 buf][2 dir][64][512]
    float* __restrict__ out, float* __restrict__ hseg, float* __restrict__ cseg,
    unsigned short* __restrict__ flags)  // [8 group][128 wave]
{
    const int bx  = blockIdx.x;
    const int dir = bx >> 7, mg = (bx >> 5) & 3, ng = bx & 31;
    const int b0 = mg * 16, p0 = ng * 64, j0 = ng * 16;
    const int tid = threadIdx.x, lane = tid & 63, kw = tid >> 6;
    const int l15 = lane & 15, koff = (lane >> 4) * 8;

    __shared__ float gbuf[4][16][68];    // [wave][m][p_local] partial gates

    // ---- one-time: B fragments into registers, pinned so they survive the loop ----
    f4 wx[4][4], wh[4][4];
    #pragma unroll
    for (int nt = 0; nt < 4; ++nt) {
        const _Float16* wrow = wcat + ((size_t)dir * 2048 + p0 + nt * 16 + l15) * 1024 + kw * 128 + koff;
        #pragma unroll
        for (int s = 0; s < 4; ++s) {
            wx[nt][s] = *(const f4*)(wrow + s * 32);
            wh[nt][s] = *(const f4*)(wrow + 512 + s * 32);
        }
    }
    #pragma unroll
    for (int nt = 0; nt < 4; ++nt)
        #pragma unroll
        for (int s = 0; s < 4; ++s) {
            asm volatile("" : "+v"(wx[nt][s]));
            asm volatile("" : "+v"(wh[nt][s]));
        }

    // ---- one-time: per-thread epilogue state (thread owns (b0+mb, j0+jj)) ----
    const int mb = tid >> 4, jj = tid & 15;
    const float* bias = dir ? b_b : b_f;
    const float bi = bias[0 * 512 + j0 + jj];
    const float bf = bias[1 * 512 + j0 + jj];
    const float bg = bias[2 * 512 + j0 + jj];
    const float bo = bias[3 * 512 + j0 + jj];
    float c = enc_c[(size_t)(b0 + mb) * 1024 + dir * 512 + j0 + jj];
    float hlast = 0.f;

    const int grp = dir * 4 + mg;
    unsigned short* gflags = flags + grp * 128;
    const unsigned* fl32   = (const unsigned*)gflags;   // 64 dwords = 128 u16
    unsigned short* myflag = gflags + ng * 4 + kw;
    _Float16* hd = h16 + (size_t)(b0 + mb) * 512 + j0 + jj;   // + bufsel per step

    // per-lane A-fragment base pointers
    const _Float16* xbase = x16 + (size_t)(b0 + l15) * NT * 512 + kw * 128 + koff;

    // prefetch x_0 fragments
    f4 xf[4];
    {
        const _Float16* xp = xbase + (size_t)(dir ? (NT - 1) : 0) * 512;
        #pragma unroll
        for (int s = 0; s < 4; ++s) xf[s] = *(const f4*)(xp + s * 32);
    }

    for (int t = 0; t < NT; ++t) {
        const int tx = dir ? (NT - 1 - t) : t;

        // ---- x-part MFMAs (independent of h -> overlaps flag propagation) ----
        f4 acc[4];
        #pragma unroll
        for (int nt = 0; nt < 4; ++nt) { acc[nt][0] = 0.f; acc[nt][1] = 0.f; acc[nt][2] = 0.f; acc[nt][3] = 0.f; }
        #pragma unroll
        for (int s = 0; s < 4; ++s) {
            h8 a = __builtin_bit_cast(h8, xf[s]);
            #pragma unroll
            for (int nt = 0; nt < 4; ++nt)
                acc[nt] = __builtin_amdgcn_mfma_f32_16x16x32_f16(a, __builtin_bit_cast(h8, wx[nt][s]), acc[nt], 0, 0, 0);
        }

        // ---- wait for all 128 producer waves of this group to publish h(t-1) ----
        if (t) {
            const unsigned tgt = (unsigned)t;
            const unsigned* fp = fl32 + lane;
            unsigned fv;
            do {
                asm volatile("global_load_dword %0, %1, off sc0 sc1\n\ts_waitcnt vmcnt(0)"
                             : "=v"(fv) : "v"(fp) : "memory");
            } while (!__all(((fv & 0xffffu) >= tgt) && ((fv >> 16) >= tgt)));
        }

        // ---- h A-fragments: coherent loads straight into registers ----
        const _Float16* hp = h16 + ((size_t)(t & 1) * 2 + dir) * 64 * 512
                                 + (size_t)(b0 + l15) * 512 + kw * 128 + koff;
        f4 hf0, hf1, hf2, hf3;
        asm volatile(
            "global_load_dwordx4 %0, %4, off sc0 sc1\n\t"
            "global_load_dwordx4 %1, %4, off offset:64 sc0 sc1\n\t"
            "global_load_dwordx4 %2, %4, off offset:128 sc0 sc1\n\t"
            "global_load_dwordx4 %3, %4, off offset:192 sc0 sc1\n\t"
            "s_waitcnt vmcnt(0)"
            : "=&v"(hf0), "=&v"(hf1), "=&v"(hf2), "=&v"(hf3)
            : "v"(hp) : "memory");

        // ---- h-part MFMAs ----
        #pragma unroll
        for (int nt = 0; nt < 4; ++nt) {
            acc[nt] = __builtin_amdgcn_mfma_f32_16x16x32_f16(__builtin_bit_cast(h8, hf0), __builtin_bit_cast(h8, wh[nt][0]), acc[nt], 0, 0, 0);
            acc[nt] = __builtin_amdgcn_mfma_f32_16x16x32_f16(__builtin_bit_cast(h8, hf1), __builtin_bit_cast(h8, wh[nt][1]), acc[nt], 0, 0, 0);
            acc[nt] = __builtin_amdgcn_mfma_f32_16x16x32_f16(__builtin_bit_cast(h8, hf2), __builtin_bit_cast(h8, wh[nt][2]), acc[nt], 0, 0, 0);
            acc[nt] = __builtin_amdgcn_mfma_f32_16x16x32_f16(__builtin_bit_cast(h8, hf3), __builtin_bit_cast(h8, wh[nt][3]), acc[nt], 0, 0, 0);
        }

        // ---- prefetch x_{t+1} fragments (normal cached loads) ----
        if (t + 1 < NT) {
            const _Float16* xp = xbase + (size_t)(dir ? (NT - 2 - t) : (t + 1)) * 512;
            #pragma unroll
            for (int s = 0; s < 4; ++s) xf[s] = *(const f4*)(xp + s * 32);
        }

        // ---- cross-wave split-K reduction via LDS ----
        __syncthreads();                       // prev step's gbuf reads done
        #pragma unroll
        for (int nt = 0; nt < 4; ++nt)
            #pragma unroll
            for (int r = 0; r < 4; ++r)
                gbuf[kw][(lane >> 4) * 4 + r][nt * 16 + l15] = acc[nt][r];
        __syncthreads();

        // ---- gates + state update (thread = (mb, jj)) ----
        float gi = bi, gf = bf, gg = bg, go = bo;
        #pragma unroll
        for (int w = 0; w < 4; ++w) {
            gi += gbuf[w][mb][jj * 4 + 0];
            gf += gbuf[w][mb][jj * 4 + 1];
            gg += gbuf[w][mb][jj * 4 + 2];
            go += gbuf[w][mb][jj * 4 + 3];
        }
        float i_ = sigm(gi), f_ = sigm(gf), o_ = sigm(go), g_ = tanhf_(gg);
        c = f_ * c + i_ * g_;
        float h = o_ * tanhf_(c);
        hlast = h;

        out[((size_t)(b0 + mb) * NT + tx) * 1024 + dir * 512 + j0 + jj] = h;

        // ---- publish h(t) coherently, then per-wave flag = t+1 ----
        {
            _Float16 hh = (_Float16)h;
            unsigned hv = (unsigned)__builtin_bit_cast(unsigned short, hh);
            _Float16* hdst = hd + ((size_t)((t + 1) & 1) * 2 + dir) * 64 * 512;
            asm volatile("global_store_short %0, %1, off sc0 sc1" :: "v"(hdst), "v"(hv) : "memory");
        }
        asm volatile("s_waitcnt vmcnt(0)" ::: "memory");
        if (lane == 0) {
            unsigned fv2 = (unsigned)(t + 1);
            asm volatile("global_store_short %0, %1, off sc0 sc1" :: "v"(myflag), "v"(fv2) : "memory");
        }
    }

    // ---- final h/c state ----
    hseg[(size_t)(b0 + mb) * 1024 + dir * 512 + j0 + jj] = hlast;
    cseg[(size_t)(b0 + mb) * 1024 + dir * 512 + j0 + jj] = c;
}

// ---------------- launcher ----------------

extern "C" void kernel_launch(void* const* d_in, const int* in_sizes, int n_in,
                              void* d_out, int out_size, void* d_ws, size_t ws_size,
                              hipStream_t stream) {
    const float* xin   = (const float*)d_in[0];
    const float* enc_h = (const float*)d_in[1];
    const float* enc_c = (const float*)d_in[2];
    const float* Wih_f = (const float*)d_in[3];
    const float* Whh_f = (const float*)d_in[4];
    const float* b_f   = (const float*)d_in[5];
    const float* Wih_b = (const float*)d_in[6];
    const float* Whh_b = (const float*)d_in[7];
    const float* b_b   = (const float*)d_in[8];

    float* out  = (float*)d_out;
    float* hseg = out + OUT0;          // final h [64,1024]
    float* cseg = hseg + 65536;        // final c [64,1024]

    const size_t X16_BYTES  = (size_t)64 * 512 * 512 * 2;        // 33,554,432
    const size_t WCAT_BYTES = (size_t)2 * 2048 * 1024 * 2;       //  8,388,608
    const size_t H16_BYTES  = (size_t)2 * 2 * 64 * 512 * 2;      //    262,144

    _Float16*       x16   = (_Float16*)d_ws;
    _Float16*       wcat  = (_Float16*)((char*)d_ws + X16_BYTES);
    _Float16*       h16   = (_Float16*)((char*)d_ws + X16_BYTES + WCAT_BYTES);
    unsigned short* flags = (unsigned short*)((char*)d_ws + X16_BYTES + WCAT_BYTES + H16_BYTES);

    xconv_k<<<dim3(16384), dim3(256), 0, stream>>>(xin, x16);
    wconv_k<<<dim3(4096), dim3(256), 0, stream>>>(Wih_f, Whh_f, Wih_b, Whh_b, wcat);
    init2_k<<<dim3(256), dim3(256), 0, stream>>>(enc_h, h16, (unsigned*)flags);
    lstm_persist<<<dim3(256), dim3(256), 0, stream>>>(x16, wcat, b_f, b_b, enc_c,
                                                      h16, out, hseg, cseg, flags);
}